// Round 6
// baseline (41.713 us; speedup 1.0000x reference)
//
#include <hip/hip_runtime.h>
#include <stdint.h>

#define BB      512
#define NCROPS  5
#define TT      8192
#define THREADS 512
#define WAVES   8
#define HPAD    257   // 256 bins + 1 pad word -> cross-wave bank decorrelation

// Order-preserving f32 -> u32 transform (ascending).
// Every real float maps to a key > 0, so 0u is a safe "masked" sentinel.
__device__ __forceinline__ uint32_t f2ord(float f) {
    uint32_t b = __float_as_uint(f);
    return (b & 0x80000000u) ? ~b : (b | 0x80000000u);
}
__device__ __forceinline__ float ord2f(uint32_t u) {
    uint32_t b = (u & 0x80000000u) ? (u & 0x7FFFFFFFu) : ~u;
    return __uint_as_float(b);
}

#define FOR4(OP) OP(u0) OP(u1) OP(u2) OP(u3)

__global__ __launch_bounds__(THREADS, 4) void topk_loss_rows(
    const float* __restrict__ scores, const int* __restrict__ label,
    const int* __restrict__ seqlen, float* __restrict__ row_loss,
    uint32_t* __restrict__ done, float* __restrict__ out)
{
    const int tid  = threadIdx.x;
    const int lane = tid & 63;
    const int wave = tid >> 6;

    __shared__ uint32_t hist[2][WAVES][HPAD];       // ~16.4 KB, double-buffered
    __shared__ uint32_t s_keys[BB];                 // (seqlen<<9)|row for ranking
    __shared__ uint32_t bc_p, bc_k;
    __shared__ uint32_t s_m[WAVES];
    __shared__ float    s_s[WAVES];
    __shared__ int      s_c[WAVES];
    __shared__ int      s_row;
    __shared__ int      s_last;

    // ---- in-block LPT schedule: rank rows by descending seqlen ----
    // Block b takes rank rb = b<256 ? b : 767-b, so blocks b and b+256
    // (same CU under round-robin XCD dispatch) get complementary lengths.
    s_keys[tid] = ((uint32_t)seqlen[tid] << 9) | (uint32_t)tid;   // unique keys
    {   // zero histogram buffer 0 in the same pre-barrier window
        uint32_t* hz = &hist[0][0][0];
        for (int i = tid; i < WAVES * HPAD; i += THREADS) hz[i] = 0u;
    }
    __syncthreads();

    {
        const uint32_t mykey = s_keys[tid];
        const uint4* kp = reinterpret_cast<const uint4*>(s_keys);
        int rank = 0;
        #pragma unroll 8
        for (int j = 0; j < BB / 4; ++j) {
            const uint4 kv = kp[j];
            rank += (int)(kv.x > mykey) + (int)(kv.y > mykey)
                  + (int)(kv.z > mykey) + (int)(kv.w > mykey);
        }
        const int rb = (blockIdx.x < 256) ? (int)blockIdx.x : (767 - (int)blockIdx.x);
        if (rank == rb) s_row = tid;
    }
    __syncthreads();

    const int row = s_row;
    const int sl  = (int)(s_keys[row] >> 9);
    const int lb  = label[row];
    const int k   = (lb == 0) ? 1 : (sl / 16 + 1);   // 1 <= k <= sl

    // ---- issue ALL conditional loads first (full MLP) ----
    const float* base = scores + (size_t)row * NCROPS * TT;
    #define LOADJ(A0,A1,A2,A3,A4, J, PRED) \
        const bool PRED = (4 * (tid + (J) * THREADS) < sl); \
        float4 A0, A1, A2, A3, A4; \
        if (PRED) { \
            const int t4 = tid + (J) * THREADS; \
            A0 = *reinterpret_cast<const float4*>(base + 0 * TT + 4 * t4); \
            A1 = *reinterpret_cast<const float4*>(base + 1 * TT + 4 * t4); \
            A2 = *reinterpret_cast<const float4*>(base + 2 * TT + 4 * t4); \
            A3 = *reinterpret_cast<const float4*>(base + 3 * TT + 4 * t4); \
            A4 = *reinterpret_cast<const float4*>(base + 4 * TT + 4 * t4); \
        }
    LOADJ(a0,b0,c0,d0,e0, 0, p0)
    LOADJ(a1,b1,c1,d1,e1, 1, p1)
    LOADJ(a2,b2,c2,d2,e2, 2, p2)
    LOADJ(a3,b3,c3,d3,e3, 3, p3)

    // ---- crop-mean + mask -> order keys in 4 named uint4 regs ----
    uint4 u0, u1, u2, u3;
    #define KEYJ(DST, A0,A1,A2,A3,A4, J, PRED) \
        if (PRED) { \
            const int t0 = 4 * (tid + (J) * THREADS); \
            float4 a; \
            a.x = (A0.x + A1.x + A2.x + A3.x + A4.x) * 0.2f; \
            a.y = (A0.y + A1.y + A2.y + A3.y + A4.y) * 0.2f; \
            a.z = (A0.z + A1.z + A2.z + A3.z + A4.z) * 0.2f; \
            a.w = (A0.w + A1.w + A2.w + A3.w + A4.w) * 0.2f; \
            DST.x = f2ord(a.x); \
            DST.y = (t0 + 1 < sl) ? f2ord(a.y) : 0u; \
            DST.z = (t0 + 2 < sl) ? f2ord(a.z) : 0u; \
            DST.w = (t0 + 3 < sl) ? f2ord(a.w) : 0u; \
        } else { \
            DST.x = 0u; DST.y = 0u; DST.z = 0u; DST.w = 0u; \
        }
    KEYJ(u0, a0,b0,c0,d0,e0, 0, p0)
    KEYJ(u1, a1,b1,c1,d1,e1, 1, p1)
    KEYJ(u2, a2,b2,c2,d2,e2, 2, p2)
    KEYJ(u3, a3,b3,c3,d3,e3, 3, p3)

    uint32_t thr;
    if (k == 1) {
        // ---- label==0 fast path: threshold = row max ----
        uint32_t mx = 0u;
        #define MAXOP(V) mx = max(mx, max(max(V.x, V.y), max(V.z, V.w)));
        FOR4(MAXOP)
        #pragma unroll
        for (int off = 32; off; off >>= 1) {
            const uint32_t o = (uint32_t)__shfl_down((int)mx, off);
            mx = max(mx, o);
        }
        if (lane == 0) s_m[wave] = mx;
        __syncthreads();
        uint32_t rowmax = s_m[0];
        #pragma unroll
        for (int w = 1; w < WAVES; ++w) rowmax = max(rowmax, s_m[w]);
        thr = rowmax;
    } else {
        // ---- MSB-first radix select, 4 rounds x 8 bits ----
        uint32_t p = 0u, kr = (uint32_t)k;
        #pragma unroll
        for (int r = 0; r < 4; ++r) {
            uint32_t* h = &hist[r & 1][wave][0];
            if (r == 0) {
                #define H0(X)  if ((X) != 0u) atomicAdd(&h[(X) >> 24], 1u);
                #define H0V(V) H0(V.x) H0(V.y) H0(V.z) H0(V.w)
                FOR4(H0V)
            } else {
                const int shp = 32 - 8 * r;   // prefix shift
                const int shd = shp - 8;      // digit shift
                #define HR(X)  if ((X) != 0u && ((X) >> shp) == p) atomicAdd(&h[((X) >> shd) & 255u], 1u);
                #define HRV(V) HR(V.x) HR(V.y) HR(V.z) HR(V.w)
                FOR4(HRV)
            }
            __syncthreads();
            if (wave == 0) {
                // combine 8 wave-hists (4 bins/lane), suffix-scan, pick digit
                uint32_t t0s = 0u, t1s = 0u, t2s = 0u, t3s = 0u;
                #pragma unroll
                for (int w = 0; w < WAVES; ++w) {
                    const uint32_t* hw = &hist[r & 1][w][0];
                    t0s += hw[4 * lane + 0];
                    t1s += hw[4 * lane + 1];
                    t2s += hw[4 * lane + 2];
                    t3s += hw[4 * lane + 3];
                }
                const uint32_t s = t0s + t1s + t2s + t3s;
                uint32_t suf = s;                         // inclusive suffix sum
                #pragma unroll
                for (int off = 1; off < 64; off <<= 1) {
                    const uint32_t v = (uint32_t)__shfl_down((int)suf, off);
                    if (lane + off < 64) suf += v;
                }
                const uint32_t E  = suf - s;              // sum over lanes > l
                const uint32_t T3 = E  + t3s;             // T(c) = cnt(keys >= bin c)
                const uint32_t T2 = T3 + t2s;
                const uint32_t T1 = T2 + t1s;
                const uint32_t T0 = T1 + t0s;
                const unsigned long long bal = __ballot(T0 >= kr);
                const int L = 63 - __clzll(bal);          // highest lane with T0 >= kr
                if (lane == L) {
                    uint32_t j, Tj, tj;
                    if      (T3 >= kr) { j = 3u; Tj = T3; tj = t3s; }
                    else if (T2 >= kr) { j = 2u; Tj = T2; tj = t2s; }
                    else if (T1 >= kr) { j = 1u; Tj = T1; tj = t1s; }
                    else               { j = 0u; Tj = T0; tj = t0s; }
                    bc_p = (p << 8) | (uint32_t)(4 * lane) | j;
                    bc_k = kr - (Tj - tj);                // rank within chosen bin
                }
            } else if (r < 3) {
                // zero the other buffer for the next round (overlaps the scan)
                uint32_t* hz = &hist[(r + 1) & 1][0][0];
                for (int i = tid - 64; i < WAVES * HPAD; i += (THREADS - 64)) hz[i] = 0u;
            }
            __syncthreads();
            p  = bc_p;
            kr = bc_k;
        }
        thr = p;   // exact bit pattern of the k-th largest key
    }

    // ---- unified epilogue: topk = sum(u>=thr) - (cnt(u>=thr)-k)*val(thr) ----
    float sg = 0.f;
    int   cg = 0;
    #define SUMOP(V) \
        if (V.x >= thr) { sg += ord2f(V.x); cg++; } \
        if (V.y >= thr) { sg += ord2f(V.y); cg++; } \
        if (V.z >= thr) { sg += ord2f(V.z); cg++; } \
        if (V.w >= thr) { sg += ord2f(V.w); cg++; }
    FOR4(SUMOP)
    #pragma unroll
    for (int off = 32; off; off >>= 1) {
        sg += __shfl_down(sg, off);
        cg += __shfl_down(cg, off);
    }
    if (lane == 0) { s_s[wave] = sg; s_c[wave] = cg; }
    __syncthreads();

    if (tid == 0) {
        float S = 0.f; int C = 0;
        #pragma unroll
        for (int w = 0; w < WAVES; ++w) { S += s_s[w]; C += s_c[w]; }
        const float kf   = ord2f(thr);
        const float topk = S - (float)(C - k) * kf;
        const float v    = topk / (float)k;
        const float y    = (float)lb;
        const float la   = fmaxf(v, 0.f) + log1pf(expf(-fabsf(v)));  // logaddexp(0,v)
        row_loss[row] = la - v * y;
        __threadfence();
        s_last = (atomicAdd(done, 1u) == (uint32_t)(BB - 1));
    }
    __syncthreads();

    // ---- last block performs the final 512 -> 1 reduction (fixed order) ----
    if (s_last) {
        __threadfence();
        float v = __hip_atomic_load(&row_loss[tid], __ATOMIC_RELAXED,
                                    __HIP_MEMORY_SCOPE_AGENT);
        #pragma unroll
        for (int off = 32; off; off >>= 1) v += __shfl_down(v, off);
        __syncthreads();
        if (lane == 0) s_s[wave] = v;
        __syncthreads();
        if (tid == 0) {
            float S = 0.f;
            #pragma unroll
            for (int w = 0; w < WAVES; ++w) S += s_s[w];
            out[0] = S * (1.0f / (float)BB);
        }
    }
}

extern "C" void kernel_launch(void* const* d_in, const int* in_sizes, int n_in,
                              void* d_out, int out_size, void* d_ws, size_t ws_size,
                              hipStream_t stream) {
    const float* scores = (const float*)d_in[0];
    const int*   label  = (const int*)d_in[1];
    const int*   seqlen = (const int*)d_in[2];
    float* out = (float*)d_out;

    float*    row_loss = (float*)d_ws;                           // 512 floats
    uint32_t* done     = (uint32_t*)((char*)d_ws + 2048);        // 1 uint

    hipMemsetAsync(done, 0, sizeof(uint32_t), stream);
    topk_loss_rows<<<BB, THREADS, 0, stream>>>(scores, label, seqlen,
                                               row_loss, done, out);
}

// Round 7
// 22.610 us; speedup vs baseline: 1.8449x; 1.8449x over previous
//
#include <hip/hip_runtime.h>
#include <stdint.h>

#define BB      512
#define NCROPS  5
#define TT      8192
#define THREADS 512
#define WAVES   8
#define HPAD    257   // 256 bins + 1 pad word -> cross-wave bank decorrelation

// Order-preserving f32 -> u32 transform (ascending).
// Every real float maps to a key > 0, so 0u is a safe "masked" sentinel.
__device__ __forceinline__ uint32_t f2ord(float f) {
    uint32_t b = __float_as_uint(f);
    return (b & 0x80000000u) ? ~b : (b | 0x80000000u);
}
__device__ __forceinline__ float ord2f(uint32_t u) {
    uint32_t b = (u & 0x80000000u) ? (u & 0x7FFFFFFFu) : ~u;
    return __uint_as_float(b);
}

#define FOR4(OP) OP(u0) OP(u1) OP(u2) OP(u3)

__global__ __launch_bounds__(THREADS, 2) void topk_loss_rows(
    const float* __restrict__ scores, const int* __restrict__ label,
    const int* __restrict__ seqlen, float* __restrict__ row_loss)
{
    const int b    = blockIdx.x;
    const int tid  = threadIdx.x;
    const int lane = tid & 63;
    const int wave = tid >> 6;

    const int sl = seqlen[b];
    const int lb = label[b];
    const int k  = (lb == 0) ? 1 : (sl / 16 + 1);   // 1 <= k <= sl

    __shared__ uint32_t hist[2][WAVES][HPAD];       // ~16.4 KB, double-buffered
    __shared__ uint32_t bc_p, bc_k;
    __shared__ uint32_t s_m[WAVES];
    __shared__ float    s_s[WAVES];
    __shared__ int      s_c[WAVES];
    // Occupancy limiter: pad LDS to ~84.6 KB total so only ONE block is
    // resident per CU. This spreads the 512 blocks across all 256 CUs and
    // makes the second generation dynamically scheduled (free LPT): a CU
    // that finishes a short row immediately pulls the next block.
    __shared__ uint32_t s_pad[17000];               // 68 KB
    if (sl == -2147483647) s_pad[tid] = 0u;         // opaque; never true

    // ---- issue ALL conditional loads first (full MLP; barrier drains) ----
    const float* base = scores + (size_t)b * NCROPS * TT;
    #define LOADJ(A0,A1,A2,A3,A4, J, PRED) \
        const bool PRED = (4 * (tid + (J) * THREADS) < sl); \
        float4 A0, A1, A2, A3, A4; \
        if (PRED) { \
            const int t4 = tid + (J) * THREADS; \
            A0 = *reinterpret_cast<const float4*>(base + 0 * TT + 4 * t4); \
            A1 = *reinterpret_cast<const float4*>(base + 1 * TT + 4 * t4); \
            A2 = *reinterpret_cast<const float4*>(base + 2 * TT + 4 * t4); \
            A3 = *reinterpret_cast<const float4*>(base + 3 * TT + 4 * t4); \
            A4 = *reinterpret_cast<const float4*>(base + 4 * TT + 4 * t4); \
        }
    LOADJ(a0,b0,c0,d0,e0, 0, p0)
    LOADJ(a1,b1,c1,d1,e1, 1, p1)
    LOADJ(a2,b2,c2,d2,e2, 2, p2)
    LOADJ(a3,b3,c3,d3,e3, 3, p3)

    // zero histogram buffer 0 while loads are in flight
    {
        uint32_t* hz = &hist[0][0][0];
        for (int i = tid; i < WAVES * HPAD; i += THREADS) hz[i] = 0u;
    }
    __syncthreads();

    // ---- crop-mean + mask -> order keys in 4 named uint4 regs ----
    uint4 u0, u1, u2, u3;
    #define KEYJ(DST, A0,A1,A2,A3,A4, J, PRED) \
        if (PRED) { \
            const int t0 = 4 * (tid + (J) * THREADS); \
            float4 a; \
            a.x = (A0.x + A1.x + A2.x + A3.x + A4.x) * 0.2f; \
            a.y = (A0.y + A1.y + A2.y + A3.y + A4.y) * 0.2f; \
            a.z = (A0.z + A1.z + A2.z + A3.z + A4.z) * 0.2f; \
            a.w = (A0.w + A1.w + A2.w + A3.w + A4.w) * 0.2f; \
            DST.x = f2ord(a.x); \
            DST.y = (t0 + 1 < sl) ? f2ord(a.y) : 0u; \
            DST.z = (t0 + 2 < sl) ? f2ord(a.z) : 0u; \
            DST.w = (t0 + 3 < sl) ? f2ord(a.w) : 0u; \
        } else { \
            DST.x = 0u; DST.y = 0u; DST.z = 0u; DST.w = 0u; \
        }
    KEYJ(u0, a0,b0,c0,d0,e0, 0, p0)
    KEYJ(u1, a1,b1,c1,d1,e1, 1, p1)
    KEYJ(u2, a2,b2,c2,d2,e2, 2, p2)
    KEYJ(u3, a3,b3,c3,d3,e3, 3, p3)

    uint32_t thr;
    if (k == 1) {
        // ---- label==0 fast path: threshold = row max ----
        uint32_t mx = 0u;
        #define MAXOP(V) mx = max(mx, max(max(V.x, V.y), max(V.z, V.w)));
        FOR4(MAXOP)
        #pragma unroll
        for (int off = 32; off; off >>= 1) {
            const uint32_t o = (uint32_t)__shfl_down((int)mx, off);
            mx = max(mx, o);
        }
        if (lane == 0) s_m[wave] = mx;
        __syncthreads();
        uint32_t rowmax = s_m[0];
        #pragma unroll
        for (int w = 1; w < WAVES; ++w) rowmax = max(rowmax, s_m[w]);
        thr = rowmax;
    } else {
        // ---- MSB-first radix select, 4 rounds x 8 bits ----
        uint32_t p = 0u, kr = (uint32_t)k;
        #pragma unroll
        for (int r = 0; r < 4; ++r) {
            uint32_t* h = &hist[r & 1][wave][0];
            if (r == 0) {
                #define H0(X)  if ((X) != 0u) atomicAdd(&h[(X) >> 24], 1u);
                #define H0V(V) H0(V.x) H0(V.y) H0(V.z) H0(V.w)
                FOR4(H0V)
            } else {
                const int shp = 32 - 8 * r;   // prefix shift
                const int shd = shp - 8;      // digit shift
                #define HR(X)  if ((X) != 0u && ((X) >> shp) == p) atomicAdd(&h[((X) >> shd) & 255u], 1u);
                #define HRV(V) HR(V.x) HR(V.y) HR(V.z) HR(V.w)
                FOR4(HRV)
            }
            __syncthreads();
            if (wave == 0) {
                // combine 8 wave-hists (4 bins/lane), suffix-scan, pick digit
                uint32_t t0s = 0u, t1s = 0u, t2s = 0u, t3s = 0u;
                #pragma unroll
                for (int w = 0; w < WAVES; ++w) {
                    const uint32_t* hw = &hist[r & 1][w][0];
                    t0s += hw[4 * lane + 0];
                    t1s += hw[4 * lane + 1];
                    t2s += hw[4 * lane + 2];
                    t3s += hw[4 * lane + 3];
                }
                const uint32_t s = t0s + t1s + t2s + t3s;
                uint32_t suf = s;                         // inclusive suffix sum
                #pragma unroll
                for (int off = 1; off < 64; off <<= 1) {
                    const uint32_t v = (uint32_t)__shfl_down((int)suf, off);
                    if (lane + off < 64) suf += v;
                }
                const uint32_t E  = suf - s;              // sum over lanes > l
                const uint32_t T3 = E  + t3s;             // T(c) = cnt(keys >= bin c)
                const uint32_t T2 = T3 + t2s;
                const uint32_t T1 = T2 + t1s;
                const uint32_t T0 = T1 + t0s;
                const unsigned long long bal = __ballot(T0 >= kr);
                const int L = 63 - __clzll(bal);          // highest lane with T0 >= kr
                if (lane == L) {
                    uint32_t j, Tj, tj;
                    if      (T3 >= kr) { j = 3u; Tj = T3; tj = t3s; }
                    else if (T2 >= kr) { j = 2u; Tj = T2; tj = t2s; }
                    else if (T1 >= kr) { j = 1u; Tj = T1; tj = t1s; }
                    else               { j = 0u; Tj = T0; tj = t0s; }
                    bc_p = (p << 8) | (uint32_t)(4 * lane) | j;
                    bc_k = kr - (Tj - tj);                // rank within chosen bin
                }
            } else if (r < 3) {
                // zero the other buffer for the next round (overlaps the scan)
                uint32_t* hz = &hist[(r + 1) & 1][0][0];
                for (int i = tid - 64; i < WAVES * HPAD; i += (THREADS - 64)) hz[i] = 0u;
            }
            __syncthreads();
            p  = bc_p;
            kr = bc_k;
        }
        thr = p;   // exact bit pattern of the k-th largest key
    }

    // ---- unified epilogue: topk = sum(u>=thr) - (cnt(u>=thr)-k)*val(thr) ----
    float sg = 0.f;
    int   cg = 0;
    #define SUMOP(V) \
        if (V.x >= thr) { sg += ord2f(V.x); cg++; } \
        if (V.y >= thr) { sg += ord2f(V.y); cg++; } \
        if (V.z >= thr) { sg += ord2f(V.z); cg++; } \
        if (V.w >= thr) { sg += ord2f(V.w); cg++; }
    FOR4(SUMOP)
    #pragma unroll
    for (int off = 32; off; off >>= 1) {
        sg += __shfl_down(sg, off);
        cg += __shfl_down(cg, off);
    }
    if (lane == 0) { s_s[wave] = sg; s_c[wave] = cg; }
    __syncthreads();

    if (tid == 0) {
        float S = 0.f; int C = 0;
        #pragma unroll
        for (int w = 0; w < WAVES; ++w) { S += s_s[w]; C += s_c[w]; }
        const float kf   = ord2f(thr);
        const float topk = S - (float)(C - k) * kf;
        const float v    = topk / (float)k;
        const float y    = (float)lb;
        const float la   = fmaxf(v, 0.f) + log1pf(expf(-fabsf(v)));  // logaddexp(0,v)
        row_loss[b] = la - v * y;
    }
}

__global__ __launch_bounds__(256) void reduce_loss(
    const float* __restrict__ row_loss, float* __restrict__ out)
{
    const int tid = threadIdx.x;
    float v = row_loss[tid] + row_loss[tid + 256];
    #pragma unroll
    for (int off = 32; off; off >>= 1) v += __shfl_down(v, off);
    __shared__ float s[4];
    if ((tid & 63) == 0) s[tid >> 6] = v;
    __syncthreads();
    if (tid == 0) out[0] = (s[0] + s[1] + s[2] + s[3]) * (1.0f / 512.0f);
}

extern "C" void kernel_launch(void* const* d_in, const int* in_sizes, int n_in,
                              void* d_out, int out_size, void* d_ws, size_t ws_size,
                              hipStream_t stream) {
    const float* scores = (const float*)d_in[0];
    const int*   label  = (const int*)d_in[1];
    const int*   seqlen = (const int*)d_in[2];
    float* out      = (float*)d_out;
    float* row_loss = (float*)d_ws;   // 512 floats

    topk_loss_rows<<<BB, THREADS, 0, stream>>>(scores, label, seqlen, row_loss);
    reduce_loss<<<1, 256, 0, stream>>>(row_loss, out);
}